// Round 8
// baseline (155.323 us; speedup 1.0000x reference)
//
#include <hip/hip_runtime.h>
#include <math.h>

#define HID 64
#define KB 9            // NUM_BINS - 1
#define NB 10
#define NTOT (128 * 20000)
#define EPT 2           // elements/thread: 20 contiguous output floats = 5 f4s
#define BLOCK 256
#define LEAKY 0.01f
#define RSTRIDE 20      // floats per region row (9 A + 9 C + 2 pad) = 5 f4s
#define TAB_FLOATS (128 + 65 * RSTRIDE)   // 128 padded thresholds + 65 regions = 1428
#define WS_BYTES (TAB_FLOATS * 4)
#define SENT 3.0e38f

typedef float v4f __attribute__((ext_vector_type(4)));

// ---------------- setup: 65 blocks x 64 threads, one region per wave ----------------
// ws[0..127]: sorted thresholds t_j = -b1_j/W1_j padded with +SENT;
// ws[128 + r*RSTRIDE + {k, KB+k}]: A[r][k], C[r][k] with logits_k(x) = A*x + C
// on region r = count(t <= x). Units iterate in ORIGINAL order (R2 bug: the
// sort must only affect the threshold array, never the (W1,b1,W2) pairing).
__global__ __launch_bounds__(64) void setup_kernel(
    const float* __restrict__ W1, const float* __restrict__ b1,
    const float* __restrict__ W2, const float* __restrict__ b2,
    float* __restrict__ ws)
{
    __shared__ float t_lds[HID], w_lds[HID], b_lds[HID], tsrt[HID];
    __shared__ float w2_lds[HID * KB];
    __shared__ float red[18 * 65];   // rows padded to 65 -> conflict-free reduce

    const int j = threadIdx.x;       // unit index (original order)
    const int r = blockIdx.x;        // region index 0..64
    const float w = W1[j], b = b1[j];
    const float t = (w != 0.0f) ? (-b / w) : -SENT;  // w==0: constant sign, park at -inf
    t_lds[j] = t; w_lds[j] = w; b_lds[j] = b;
    #pragma unroll
    for (int q = j; q < HID * KB; q += 64) w2_lds[q] = W2[q];
    __syncthreads();

    int rank = 0;                    // rank sort (unique ranks via index tiebreak)
    for (int i = 0; i < HID; ++i) {
        float ti = t_lds[i];
        rank += (ti < t || (ti == t && i < j)) ? 1 : 0;
    }
    tsrt[rank] = t;
    __syncthreads();

    float xm;   // point strictly inside region r
    if (r == 0)        xm = tsrt[0] - 1.0f;
    else if (r == HID) xm = tsrt[HID - 1] + 1.0f;
    else               xm = 0.5f * (tsrt[r - 1] + tsrt[r]);

    const float s = (fmaf(w, xm, b) >= 0.0f) ? 1.0f : LEAKY;
    #pragma unroll
    for (int k = 0; k < KB; ++k) {
        const float w2s = w2_lds[j * KB + k] * s;
        red[(2 * k) * 65 + j]     = w2s * w;   // A contribution
        red[(2 * k + 1) * 65 + j] = w2s * b;   // C contribution
    }
    __syncthreads();

    if (j < 18) {   // threads 0..17 each sum one row of 64 (deterministic order)
        float acc = 0.0f;
        for (int i = 0; i < HID; ++i) acc += red[j * 65 + i];
        const int k = j >> 1;
        if (j & 1) ws[128 + r * RSTRIDE + KB + k] = acc + b2[k];  // C
        else       ws[128 + r * RSTRIDE + k]      = acc;          // A
    }
    if (r == 0) { ws[j] = tsrt[j]; ws[64 + j] = SENT; }
}

// ---------------- main: table lookup + softmax, DIRECT stores (A/B vs R7) ----------------
// Single lever vs R7: so[] staging removed; each thread stores its 20
// contiguous output floats directly (5 f4 stores, 16B-aligned). LDS = 5.8 KB
// -> 8 blocks/CU (wave-slot capped).
__global__ __launch_bounds__(BLOCK) void main_kernel(
    const float* __restrict__ expr, const float* __restrict__ ws,
    float* __restrict__ out)
{
    __shared__ float ts[128];
    __shared__ float tab[65 * RSTRIDE];

    const int tid = threadIdx.x;
    for (int t = tid; t < TAB_FLOATS; t += BLOCK) {
        float v = ws[t];
        if (t < 128) ts[t] = v; else tab[t - 128] = v;
    }
    __syncthreads();

    const int i0 = (blockIdx.x * BLOCK + tid) * EPT;
    const float2 xv = *(const float2*)(expr + i0);
    float x[EPT] = {xv.x, xv.y};
    float o[EPT * NB];
    float msk[EPT];
    #pragma unroll
    for (int e = 0; e < EPT; ++e) {
        const float xe = x[e];
        // region = count(sorted thresholds <= xe); padding keeps all 7 probes in-bounds
        int idx = 0;
        #pragma unroll
        for (int s = 64; s >= 1; s >>= 1)
            idx += (ts[idx + s - 1] <= xe) ? s : 0;
        // whole 20-float row as 5 batched b128 LDS reads (mostly broadcast: 90% zeros)
        const v4f* rowv = (const v4f*)(tab + idx * RSTRIDE);
        v4f r0 = rowv[0], r1 = rowv[1], r2 = rowv[2], r3 = rowv[3], r4 = rowv[4];
        const float A[KB] = {r0.x, r0.y, r0.z, r0.w, r1.x, r1.y, r1.z, r1.w, r2.x};
        const float C[KB] = {r2.y, r2.z, r2.w, r3.x, r3.y, r3.z, r3.w, r4.x, r4.y};
        float lg[KB];
        #pragma unroll
        for (int k = 0; k < KB; ++k) lg[k] = fmaf(A[k], xe, C[k]);
        float m = lg[0];
        #pragma unroll
        for (int k = 1; k < KB; ++k) m = fmaxf(m, lg[k]);
        float p[KB];
        float s = 0.0f;
        #pragma unroll
        for (int k = 0; k < KB; ++k) { p[k] = __expf(lg[k] - m); s += p[k]; }
        const float rcp = __frcp_rn(s);
        const bool nz = (xe != 0.0f);
        msk[e] = nz ? 1.0f : 0.0f;
        o[e * NB] = nz ? 0.0f : 1.0f;
        #pragma unroll
        for (int k = 0; k < KB; ++k) o[e * NB + 1 + k] = nz ? p[k] * rcp : 0.0f;
    }

    // probs: 20 contiguous floats per thread, direct f4 stores
    float4* dst = (float4*)(out + (size_t)i0 * NB);
    #pragma unroll
    for (int q = 0; q < 5; ++q) dst[q] = ((const float4*)o)[q];
    // mask output: lane-contiguous float2
    *(float2*)(out + (size_t)NTOT * NB + i0) = make_float2(msk[0], msk[1]);
}

// ---------------- fallback if d_ws too small: self-contained, per-block table ----------------
__global__ __launch_bounds__(BLOCK) void fused_kernel(
    const float* __restrict__ expr,
    const float* __restrict__ W1, const float* __restrict__ b1,
    const float* __restrict__ W2, const float* __restrict__ b2,
    float* __restrict__ out)
{
    __shared__ float ts[128];
    __shared__ float tab[65 * RSTRIDE];
    __shared__ float st[HID], sw[HID], sb[HID], tsrt[HID];
    const int tid = threadIdx.x;
    if (tid < HID) {
        float w = W1[tid], b = b1[tid];
        st[tid] = (w != 0.0f) ? (-b / w) : -SENT;
        sw[tid] = w; sb[tid] = b;
    }
    __syncthreads();
    if (tid < HID) {
        float t = st[tid];
        int r = 0;
        for (int i = 0; i < HID; ++i) {
            float ti = st[i];
            r += (ti < t || (ti == t && i < tid)) ? 1 : 0;
        }
        tsrt[r] = t;
    }
    __syncthreads();
    if (tid < 128) ts[tid] = (tid < HID) ? tsrt[tid] : SENT;
    for (int item = tid; item < 65 * KB; item += BLOCK) {
        int r = item / KB, k = item - r * KB;
        float xm;
        if (r == 0)        xm = tsrt[0] - 1.0f;
        else if (r == HID) xm = tsrt[HID - 1] + 1.0f;
        else               xm = 0.5f * (tsrt[r - 1] + tsrt[r]);
        float A = 0.0f, C = b2[k];
        for (int j = 0; j < HID; ++j) {
            float w = sw[j], bb = sb[j];
            float s = (fmaf(w, xm, bb) >= 0.0f) ? 1.0f : LEAKY;
            float w2s = W2[j * KB + k] * s;
            A = fmaf(w2s, w, A);
            C = fmaf(w2s, bb, C);
        }
        tab[r * RSTRIDE + k] = A;
        tab[r * RSTRIDE + KB + k] = C;
    }
    __syncthreads();
    const int i0 = (blockIdx.x * BLOCK + tid) * EPT;
    const float2 xv = *(const float2*)(expr + i0);
    float x[EPT] = {xv.x, xv.y};
    float o[EPT * NB]; float msk[EPT];
    #pragma unroll
    for (int e = 0; e < EPT; ++e) {
        const float xe = x[e];
        int idx = 0;
        #pragma unroll
        for (int s = 64; s >= 1; s >>= 1) idx += (ts[idx + s - 1] <= xe) ? s : 0;
        const float* row = tab + idx * RSTRIDE;
        float lg[KB];
        #pragma unroll
        for (int k = 0; k < KB; ++k) lg[k] = fmaf(row[k], xe, row[KB + k]);
        float m = lg[0];
        #pragma unroll
        for (int k = 1; k < KB; ++k) m = fmaxf(m, lg[k]);
        float p[KB]; float s = 0.0f;
        #pragma unroll
        for (int k = 0; k < KB; ++k) { p[k] = __expf(lg[k] - m); s += p[k]; }
        const float rcp = __frcp_rn(s);
        const bool nz = (xe != 0.0f);
        msk[e] = nz ? 1.0f : 0.0f;
        o[e * NB] = nz ? 0.0f : 1.0f;
        #pragma unroll
        for (int k = 0; k < KB; ++k) o[e * NB + 1 + k] = nz ? p[k] * rcp : 0.0f;
    }
    float* dst = out + (size_t)i0 * NB;
    #pragma unroll
    for (int q = 0; q < EPT * NB / 4; ++q) ((float4*)dst)[q] = ((const float4*)o)[q];
    *(float2*)(out + (size_t)NTOT * NB + i0) = make_float2(msk[0], msk[1]);
}

extern "C" void kernel_launch(void* const* d_in, const int* in_sizes, int n_in,
                              void* d_out, int out_size, void* d_ws, size_t ws_size,
                              hipStream_t stream) {
    const float* expr = (const float*)d_in[0];
    const float* W1   = (const float*)d_in[1];
    const float* b1   = (const float*)d_in[2];
    const float* W2   = (const float*)d_in[3];
    const float* b2   = (const float*)d_in[4];
    float* out = (float*)d_out;
    const int nblocks = NTOT / (BLOCK * EPT);  // 5000

    if (ws_size >= (size_t)WS_BYTES) {
        float* ws = (float*)d_ws;
        setup_kernel<<<65, 64, 0, stream>>>(W1, b1, W2, b2, ws);
        main_kernel<<<nblocks, BLOCK, 0, stream>>>(expr, ws, out);
    } else {
        fused_kernel<<<nblocks, BLOCK, 0, stream>>>(expr, W1, b1, W2, b2, out);
    }
}

// Round 9
// 140.797 us; speedup vs baseline: 1.1032x; 1.1032x over previous
//
#include <hip/hip_runtime.h>
#include <math.h>

#define HID 64
#define KB 9            // NUM_BINS - 1
#define NB 10
#define NTOT (128 * 20000)
#define EPT 2           // elements/thread: 20 contiguous output floats = 5 f4s
#define BLOCK 256
#define LEAKY 0.01f
#define RSTRIDE 20      // floats per region row (9 A + 9 C + 2 pad) = 5 f4s
#define SENT 3.0e38f
#define LOG2E 1.44269504088896f

// bucket LUT for region search
#define NBUK 2048
#define BLO (-6.0f)
#define BW (12.0f / 2048.0f)
#define BSCALE (2048.0f / 12.0f)

#define TAB_U32 (128 + 65 * RSTRIDE)      // 1428 u32: 128 thresholds + 65 rows
#define WS_U32 (TAB_U32 + NBUK / 4)       // + 512 u32 of u8 buckets = 1940 (= 485 f4)
#define WS_BYTES (WS_U32 * 4)

typedef float v4f __attribute__((ext_vector_type(4)));

// ---------------- setup: 97 blocks x 64 threads ----------------
// blocks 0..64: region r -> ws[128 + r*RSTRIDE + {k, KB+k}] = (A, C)*log2e,
//   logits2_k(x) = A'x + C' (base-2). Units in ORIGINAL order (R2 lesson).
// blocks 65..96: bucket b -> region at (edge_b - 0.5*bucket) as u8;
//   bucket[0] forced 0 so x < lo scans from the start (exact).
// ws[0..127]: sorted thresholds padded with +SENT.
__global__ __launch_bounds__(64) void setup_kernel(
    const float* __restrict__ W1, const float* __restrict__ b1,
    const float* __restrict__ W2, const float* __restrict__ b2,
    float* __restrict__ ws)
{
    __shared__ float t_lds[HID], w_lds[HID], b_lds[HID], tsrt[HID];
    __shared__ float w2_lds[HID * KB];
    __shared__ float red[18 * 65];   // rows padded to 65 -> conflict-free reduce

    const int j = threadIdx.x;       // unit index (original order)
    const int blk = blockIdx.x;
    const float w = W1[j], b = b1[j];
    const float t = (w != 0.0f) ? (-b / w) : -SENT;  // w==0: constant sign, park at -inf
    t_lds[j] = t; w_lds[j] = w; b_lds[j] = b;
    if (blk < 65) {
        #pragma unroll
        for (int q = j; q < HID * KB; q += 64) w2_lds[q] = W2[q];
    }
    __syncthreads();

    int rank = 0;                    // rank sort (unique ranks via index tiebreak)
    for (int i = 0; i < HID; ++i) {
        float ti = t_lds[i];
        rank += (ti < t || (ti == t && i < j)) ? 1 : 0;
    }
    tsrt[rank] = t;
    __syncthreads();

    if (blk >= 65) {                 // bucket fill
        const int bb = (blk - 65) * 64 + j;
        const float edge = BLO + ((float)bb - 0.5f) * BW;  // half-bucket left margin
        int cnt = 0;
        for (int i = 0; i < HID; ++i) cnt += (tsrt[i] <= edge) ? 1 : 0;
        ((unsigned char*)(ws + TAB_U32))[bb] = (bb == 0) ? 0 : (unsigned char)cnt;
        return;
    }

    const int r = blk;               // region index 0..64
    float xm;                        // point strictly inside region r
    if (r == 0)        xm = tsrt[0] - 1.0f;
    else if (r == HID) xm = tsrt[HID - 1] + 1.0f;
    else               xm = 0.5f * (tsrt[r - 1] + tsrt[r]);

    const float s = (fmaf(w, xm, b) >= 0.0f) ? 1.0f : LEAKY;
    #pragma unroll
    for (int k = 0; k < KB; ++k) {
        const float w2s = w2_lds[j * KB + k] * s;
        red[(2 * k) * 65 + j]     = w2s * w;   // A contribution
        red[(2 * k + 1) * 65 + j] = w2s * b;   // C contribution
    }
    __syncthreads();

    if (j < 18) {   // threads 0..17 each sum one row of 64 (deterministic order)
        float acc = 0.0f;
        for (int i = 0; i < HID; ++i) acc += red[j * 65 + i];
        const int k = j >> 1;
        if (j & 1) ws[128 + r * RSTRIDE + KB + k] = (acc + b2[k]) * LOG2E;  // C'
        else       ws[128 + r * RSTRIDE + k]      = acc * LOG2E;            // A'
    }
    if (r == 0) { ws[j] = tsrt[j]; ws[64 + j] = SENT; }
}

// ---------------- main: bucket search + exp2 softmax, R7 store path frozen ----------------
__global__ __launch_bounds__(BLOCK) void main_kernel(
    const float* __restrict__ expr, const float* __restrict__ ws,
    float* __restrict__ out)
{
    __shared__ __align__(16) unsigned int sdata[WS_U32];   // ts | tab | buckets
    __shared__ v4f so[BLOCK * 5];    // identity staging (R7)

    const int tid = threadIdx.x;
    #pragma unroll
    for (int t = tid; t < WS_U32 / 4; t += BLOCK)          // 485 f4s, 2 rounds
        ((v4f*)sdata)[t] = ((const v4f*)ws)[t];
    __syncthreads();

    const float* ts  = (const float*)sdata;
    const float* tab = (const float*)sdata + 128;
    const unsigned char* buk = (const unsigned char*)(sdata + TAB_U32);

    const int i0 = (blockIdx.x * BLOCK + tid) * EPT;
    const float2 xv = *(const float2*)(expr + i0);
    float x[EPT] = {xv.x, xv.y};
    float o[EPT * NB];
    float msk[EPT];
    #pragma unroll
    for (int e = 0; e < EPT; ++e) {
        const float xe = x[e];
        // bucket start (guaranteed <= region(xe)), then exact forward scan
        const float fb = fminf(2047.0f, fmaxf(0.0f, (xe - BLO) * BSCALE));
        int idx = buk[(int)fb];
        while (ts[idx] <= xe) ++idx;   // ts padded with SENT -> terminates, idx<=64
        const v4f* rowv = (const v4f*)(tab + idx * RSTRIDE);
        v4f r0 = rowv[0], r1 = rowv[1], r2 = rowv[2], r3 = rowv[3], r4 = rowv[4];
        const float A[KB] = {r0.x, r0.y, r0.z, r0.w, r1.x, r1.y, r1.z, r1.w, r2.x};
        const float C[KB] = {r2.y, r2.z, r2.w, r3.x, r3.y, r3.z, r3.w, r4.x, r4.y};
        float lg[KB];   // base-2 logits (table pre-scaled by log2e)
        #pragma unroll
        for (int k = 0; k < KB; ++k) lg[k] = fmaf(A[k], xe, C[k]);
        float m = lg[0];
        #pragma unroll
        for (int k = 1; k < KB; ++k) m = fmaxf(m, lg[k]);
        float p[KB];
        float s = 0.0f;
        #pragma unroll
        for (int k = 0; k < KB; ++k) { p[k] = exp2f(lg[k] - m); s += p[k]; }
        const float rcp = __frcp_rn(s);
        const bool nz = (xe != 0.0f);
        msk[e] = nz ? 1.0f : 0.0f;
        o[e * NB] = nz ? 0.0f : 1.0f;
        #pragma unroll
        for (int k = 0; k < KB; ++k) o[e * NB + 1 + k] = nz ? p[k] * rcp : 0.0f;
    }

    // mask output: lane-contiguous float2
    *(float2*)(out + (size_t)NTOT * NB + i0) = make_float2(msk[0], msk[1]);

    // probs: identity LDS staging (thread's 20 floats = 5 f4s), coalesced readback
    #pragma unroll
    for (int q = 0; q < 5; ++q) so[tid * 5 + q] = ((const v4f*)o)[q];
    __syncthreads();
    float* gout = out + (size_t)blockIdx.x * (BLOCK * EPT * NB);
    #pragma unroll
    for (int q = 0; q < 5; ++q) {
        const int g = q * BLOCK + tid;       // linear == physical (identity)
        ((v4f*)gout)[g] = so[g];
    }
}

// ---------------- fallback if d_ws too small: self-contained, per-block table ----------------
__global__ __launch_bounds__(BLOCK) void fused_kernel(
    const float* __restrict__ expr,
    const float* __restrict__ W1, const float* __restrict__ b1,
    const float* __restrict__ W2, const float* __restrict__ b2,
    float* __restrict__ out)
{
    __shared__ float ts[128];
    __shared__ float tab[65 * RSTRIDE];
    __shared__ float st[HID], sw[HID], sb[HID], tsrt[HID];
    const int tid = threadIdx.x;
    if (tid < HID) {
        float w = W1[tid], b = b1[tid];
        st[tid] = (w != 0.0f) ? (-b / w) : -SENT;
        sw[tid] = w; sb[tid] = b;
    }
    __syncthreads();
    if (tid < HID) {
        float t = st[tid];
        int r = 0;
        for (int i = 0; i < HID; ++i) {
            float ti = st[i];
            r += (ti < t || (ti == t && i < tid)) ? 1 : 0;
        }
        tsrt[r] = t;
    }
    __syncthreads();
    if (tid < 128) ts[tid] = (tid < HID) ? tsrt[tid] : SENT;
    for (int item = tid; item < 65 * KB; item += BLOCK) {
        int r = item / KB, k = item - r * KB;
        float xm;
        if (r == 0)        xm = tsrt[0] - 1.0f;
        else if (r == HID) xm = tsrt[HID - 1] + 1.0f;
        else               xm = 0.5f * (tsrt[r - 1] + tsrt[r]);
        float A = 0.0f, C = b2[k];
        for (int j = 0; j < HID; ++j) {
            float w = sw[j], bb = sb[j];
            float s = (fmaf(w, xm, bb) >= 0.0f) ? 1.0f : LEAKY;
            float w2s = W2[j * KB + k] * s;
            A = fmaf(w2s, w, A);
            C = fmaf(w2s, bb, C);
        }
        tab[r * RSTRIDE + k] = A;
        tab[r * RSTRIDE + KB + k] = C;
    }
    __syncthreads();
    const int i0 = (blockIdx.x * BLOCK + tid) * EPT;
    const float2 xv = *(const float2*)(expr + i0);
    float x[EPT] = {xv.x, xv.y};
    float o[EPT * NB]; float msk[EPT];
    #pragma unroll
    for (int e = 0; e < EPT; ++e) {
        const float xe = x[e];
        int idx = 0;
        #pragma unroll
        for (int s = 64; s >= 1; s >>= 1) idx += (ts[idx + s - 1] <= xe) ? s : 0;
        const float* row = tab + idx * RSTRIDE;
        float lg[KB];
        #pragma unroll
        for (int k = 0; k < KB; ++k) lg[k] = fmaf(row[k], xe, row[KB + k]);
        float m = lg[0];
        #pragma unroll
        for (int k = 1; k < KB; ++k) m = fmaxf(m, lg[k]);
        float p[KB]; float s = 0.0f;
        #pragma unroll
        for (int k = 0; k < KB; ++k) { p[k] = __expf(lg[k] - m); s += p[k]; }
        const float rcp = __frcp_rn(s);
        const bool nz = (xe != 0.0f);
        msk[e] = nz ? 1.0f : 0.0f;
        o[e * NB] = nz ? 0.0f : 1.0f;
        #pragma unroll
        for (int k = 0; k < KB; ++k) o[e * NB + 1 + k] = nz ? p[k] * rcp : 0.0f;
    }
    float* dst = out + (size_t)i0 * NB;
    #pragma unroll
    for (int q = 0; q < EPT * NB / 4; ++q) ((float4*)dst)[q] = ((const float4*)o)[q];
    *(float2*)(out + (size_t)NTOT * NB + i0) = make_float2(msk[0], msk[1]);
}

extern "C" void kernel_launch(void* const* d_in, const int* in_sizes, int n_in,
                              void* d_out, int out_size, void* d_ws, size_t ws_size,
                              hipStream_t stream) {
    const float* expr = (const float*)d_in[0];
    const float* W1   = (const float*)d_in[1];
    const float* b1   = (const float*)d_in[2];
    const float* W2   = (const float*)d_in[3];
    const float* b2   = (const float*)d_in[4];
    float* out = (float*)d_out;
    const int nblocks = NTOT / (BLOCK * EPT);  // 5000

    if (ws_size >= (size_t)WS_BYTES) {
        float* ws = (float*)d_ws;
        setup_kernel<<<65 + NBUK / 64, 64, 0, stream>>>(W1, b1, W2, b2, ws);
        main_kernel<<<nblocks, BLOCK, 0, stream>>>(expr, ws, out);
    } else {
        fused_kernel<<<nblocks, BLOCK, 0, stream>>>(expr, W1, b1, W2, b2, out);
    }
}

// Round 10
// 137.979 us; speedup vs baseline: 1.1257x; 1.0204x over previous
//
#include <hip/hip_runtime.h>
#include <math.h>

#define HID 64
#define KB 9            // NUM_BINS - 1
#define NB 10
#define NTOT (128 * 20000)
#define EPT 2           // elements/thread/tile: 20 contiguous output floats = 5 f4s
#define NTILE 4         // tiles per block (persistent-ish blocks, amortized staging)
#define BLOCK 256
#define LEAKY 0.01f
#define RSTRIDE 20      // floats per region row (9 A + 9 C + 2 pad) = 5 f4s
#define SENT 3.0e38f
#define LOG2E 1.44269504088896f

// bucket LUT for region search
#define NBUK 2048
#define BLO (-6.0f)
#define BW (12.0f / 2048.0f)
#define BSCALE (2048.0f / 12.0f)

#define TAB_U32 (128 + 65 * RSTRIDE)      // 1428 u32: 128 thresholds + 65 rows
#define WS_U32 (TAB_U32 + NBUK / 4)       // + 512 u32 of u8 buckets = 1940 (= 485 f4)
#define WS_BYTES (WS_U32 * 4)

typedef float v4f __attribute__((ext_vector_type(4)));

// ---------------- setup: 97 blocks x 64 threads (unchanged from R9) ----------------
__global__ __launch_bounds__(64) void setup_kernel(
    const float* __restrict__ W1, const float* __restrict__ b1,
    const float* __restrict__ W2, const float* __restrict__ b2,
    float* __restrict__ ws)
{
    __shared__ float t_lds[HID], w_lds[HID], b_lds[HID], tsrt[HID];
    __shared__ float w2_lds[HID * KB];
    __shared__ float red[18 * 65];   // rows padded to 65 -> conflict-free reduce

    const int j = threadIdx.x;       // unit index (original order)
    const int blk = blockIdx.x;
    const float w = W1[j], b = b1[j];
    const float t = (w != 0.0f) ? (-b / w) : -SENT;  // w==0: constant sign, park at -inf
    t_lds[j] = t; w_lds[j] = w; b_lds[j] = b;
    if (blk < 65) {
        #pragma unroll
        for (int q = j; q < HID * KB; q += 64) w2_lds[q] = W2[q];
    }
    __syncthreads();

    int rank = 0;                    // rank sort (unique ranks via index tiebreak)
    for (int i = 0; i < HID; ++i) {
        float ti = t_lds[i];
        rank += (ti < t || (ti == t && i < j)) ? 1 : 0;
    }
    tsrt[rank] = t;
    __syncthreads();

    if (blk >= 65) {                 // bucket fill
        const int bb = (blk - 65) * 64 + j;
        const float edge = BLO + ((float)bb - 0.5f) * BW;  // half-bucket left margin
        int cnt = 0;
        for (int i = 0; i < HID; ++i) cnt += (tsrt[i] <= edge) ? 1 : 0;
        ((unsigned char*)(ws + TAB_U32))[bb] = (bb == 0) ? 0 : (unsigned char)cnt;
        return;
    }

    const int r = blk;               // region index 0..64
    float xm;                        // point strictly inside region r
    if (r == 0)        xm = tsrt[0] - 1.0f;
    else if (r == HID) xm = tsrt[HID - 1] + 1.0f;
    else               xm = 0.5f * (tsrt[r - 1] + tsrt[r]);

    const float s = (fmaf(w, xm, b) >= 0.0f) ? 1.0f : LEAKY;
    #pragma unroll
    for (int k = 0; k < KB; ++k) {
        const float w2s = w2_lds[j * KB + k] * s;
        red[(2 * k) * 65 + j]     = w2s * w;   // A contribution
        red[(2 * k + 1) * 65 + j] = w2s * b;   // C contribution
    }
    __syncthreads();

    if (j < 18) {   // threads 0..17 each sum one row of 64 (deterministic order)
        float acc = 0.0f;
        for (int i = 0; i < HID; ++i) acc += red[j * 65 + i];
        const int k = j >> 1;
        if (j & 1) ws[128 + r * RSTRIDE + KB + k] = (acc + b2[k]) * LOG2E;  // C'
        else       ws[128 + r * RSTRIDE + k]      = acc * LOG2E;            // A'
    }
    if (r == 0) { ws[j] = tsrt[j]; ws[64 + j] = SENT; }
}

// ---------------- main: 4 tiles/block, pipelined loads, R9 compute + R7 stores ----------------
__global__ __launch_bounds__(BLOCK) void main_kernel(
    const float* __restrict__ expr, const float* __restrict__ ws,
    float* __restrict__ out)
{
    __shared__ __align__(16) unsigned int sdata[WS_U32];   // ts | tab | buckets
    __shared__ v4f so[BLOCK * 5];    // identity staging (R7), reused across tiles

    const int tid = threadIdx.x;
    #pragma unroll
    for (int t = tid; t < WS_U32 / 4; t += BLOCK)          // staged ONCE per block
        ((v4f*)sdata)[t] = ((const v4f*)ws)[t];

    const float* ts  = (const float*)sdata;
    const float* tab = (const float*)sdata + 128;
    const unsigned char* buk = (const unsigned char*)(sdata + TAB_U32);

    const int tile0 = blockIdx.x * NTILE;
    // issue tile 0's load before the staging barrier (latency overlaps barrier)
    float2 xv = *(const float2*)(expr + ((size_t)tile0 * BLOCK + tid) * EPT);
    __syncthreads();

    #pragma unroll
    for (int tt = 0; tt < NTILE; ++tt) {
        const int tile = tile0 + tt;
        const size_t i0 = ((size_t)tile * BLOCK + tid) * EPT;
        // pipeline: issue next tile's load before this tile's compute+stores
        float2 xv_next;
        if (tt + 1 < NTILE)
            xv_next = *(const float2*)(expr + (i0 + (size_t)BLOCK * EPT));

        float x[EPT] = {xv.x, xv.y};
        float o[EPT * NB];
        float msk[EPT];
        #pragma unroll
        for (int e = 0; e < EPT; ++e) {
            const float xe = x[e];
            // bucket start (guaranteed <= region(xe)), then exact forward scan
            const float fb = fminf(2047.0f, fmaxf(0.0f, (xe - BLO) * BSCALE));
            int idx = buk[(int)fb];
            while (ts[idx] <= xe) ++idx;   // ts padded with SENT -> terminates, idx<=64
            const v4f* rowv = (const v4f*)(tab + idx * RSTRIDE);
            v4f r0 = rowv[0], r1 = rowv[1], r2 = rowv[2], r3 = rowv[3], r4 = rowv[4];
            const float A[KB] = {r0.x, r0.y, r0.z, r0.w, r1.x, r1.y, r1.z, r1.w, r2.x};
            const float C[KB] = {r2.y, r2.z, r2.w, r3.x, r3.y, r3.z, r3.w, r4.x, r4.y};
            float lg[KB];   // base-2 logits (table pre-scaled by log2e)
            #pragma unroll
            for (int k = 0; k < KB; ++k) lg[k] = fmaf(A[k], xe, C[k]);
            float m = lg[0];
            #pragma unroll
            for (int k = 1; k < KB; ++k) m = fmaxf(m, lg[k]);
            float p[KB];
            float s = 0.0f;
            #pragma unroll
            for (int k = 0; k < KB; ++k) { p[k] = exp2f(lg[k] - m); s += p[k]; }
            const float rcp = __frcp_rn(s);
            const bool nz = (xe != 0.0f);
            msk[e] = nz ? 1.0f : 0.0f;
            o[e * NB] = nz ? 0.0f : 1.0f;
            #pragma unroll
            for (int k = 0; k < KB; ++k) o[e * NB + 1 + k] = nz ? p[k] * rcp : 0.0f;
        }

        // mask output: lane-contiguous float2
        *(float2*)(out + (size_t)NTOT * NB + i0) = make_float2(msk[0], msk[1]);

        // probs: identity LDS staging (thread's 20 floats = 5 f4s), coalesced readback
        if (tt > 0) __syncthreads();         // WAR: prev tile's readback done
        #pragma unroll
        for (int q = 0; q < 5; ++q) so[tid * 5 + q] = ((const v4f*)o)[q];
        __syncthreads();
        float* gout = out + (size_t)tile * (BLOCK * EPT * NB);
        #pragma unroll
        for (int q = 0; q < 5; ++q) {
            const int g = q * BLOCK + tid;   // linear == physical (identity)
            ((v4f*)gout)[g] = so[g];
        }
        xv = xv_next;
    }
}

// ---------------- fallback if d_ws too small: self-contained, per-block table ----------------
__global__ __launch_bounds__(BLOCK) void fused_kernel(
    const float* __restrict__ expr,
    const float* __restrict__ W1, const float* __restrict__ b1,
    const float* __restrict__ W2, const float* __restrict__ b2,
    float* __restrict__ out)
{
    __shared__ float ts[128];
    __shared__ float tab[65 * RSTRIDE];
    __shared__ float st[HID], sw[HID], sb[HID], tsrt[HID];
    const int tid = threadIdx.x;
    if (tid < HID) {
        float w = W1[tid], b = b1[tid];
        st[tid] = (w != 0.0f) ? (-b / w) : -SENT;
        sw[tid] = w; sb[tid] = b;
    }
    __syncthreads();
    if (tid < HID) {
        float t = st[tid];
        int r = 0;
        for (int i = 0; i < HID; ++i) {
            float ti = st[i];
            r += (ti < t || (ti == t && i < tid)) ? 1 : 0;
        }
        tsrt[r] = t;
    }
    __syncthreads();
    if (tid < 128) ts[tid] = (tid < HID) ? tsrt[tid] : SENT;
    for (int item = tid; item < 65 * KB; item += BLOCK) {
        int r = item / KB, k = item - r * KB;
        float xm;
        if (r == 0)        xm = tsrt[0] - 1.0f;
        else if (r == HID) xm = tsrt[HID - 1] + 1.0f;
        else               xm = 0.5f * (tsrt[r - 1] + tsrt[r]);
        float A = 0.0f, C = b2[k];
        for (int j = 0; j < HID; ++j) {
            float w = sw[j], bb = sb[j];
            float s = (fmaf(w, xm, bb) >= 0.0f) ? 1.0f : LEAKY;
            float w2s = W2[j * KB + k] * s;
            A = fmaf(w2s, w, A);
            C = fmaf(w2s, bb, C);
        }
        tab[r * RSTRIDE + k] = A;
        tab[r * RSTRIDE + KB + k] = C;
    }
    __syncthreads();
    const int i0 = (blockIdx.x * BLOCK + tid) * EPT;
    const float2 xv = *(const float2*)(expr + i0);
    float x[EPT] = {xv.x, xv.y};
    float o[EPT * NB]; float msk[EPT];
    #pragma unroll
    for (int e = 0; e < EPT; ++e) {
        const float xe = x[e];
        int idx = 0;
        #pragma unroll
        for (int s = 64; s >= 1; s >>= 1) idx += (ts[idx + s - 1] <= xe) ? s : 0;
        const float* row = tab + idx * RSTRIDE;
        float lg[KB];
        #pragma unroll
        for (int k = 0; k < KB; ++k) lg[k] = fmaf(row[k], xe, row[KB + k]);
        float m = lg[0];
        #pragma unroll
        for (int k = 1; k < KB; ++k) m = fmaxf(m, lg[k]);
        float p[KB]; float s = 0.0f;
        #pragma unroll
        for (int k = 0; k < KB; ++k) { p[k] = __expf(lg[k] - m); s += p[k]; }
        const float rcp = __frcp_rn(s);
        const bool nz = (xe != 0.0f);
        msk[e] = nz ? 1.0f : 0.0f;
        o[e * NB] = nz ? 0.0f : 1.0f;
        #pragma unroll
        for (int k = 0; k < KB; ++k) o[e * NB + 1 + k] = nz ? p[k] * rcp : 0.0f;
    }
    float* dst = out + (size_t)i0 * NB;
    #pragma unroll
    for (int q = 0; q < EPT * NB / 4; ++q) ((float4*)dst)[q] = ((const float4*)o)[q];
    *(float2*)(out + (size_t)NTOT * NB + i0) = make_float2(msk[0], msk[1]);
}

extern "C" void kernel_launch(void* const* d_in, const int* in_sizes, int n_in,
                              void* d_out, int out_size, void* d_ws, size_t ws_size,
                              hipStream_t stream) {
    const float* expr = (const float*)d_in[0];
    const float* W1   = (const float*)d_in[1];
    const float* b1   = (const float*)d_in[2];
    const float* W2   = (const float*)d_in[3];
    const float* b2   = (const float*)d_in[4];
    float* out = (float*)d_out;

    if (ws_size >= (size_t)WS_BYTES) {
        float* ws = (float*)d_ws;
        setup_kernel<<<65 + NBUK / 64, 64, 0, stream>>>(W1, b1, W2, b2, ws);
        main_kernel<<<NTOT / (BLOCK * EPT * NTILE), BLOCK, 0, stream>>>(expr, ws, out);  // 1250
    } else {
        fused_kernel<<<NTOT / (BLOCK * EPT), BLOCK, 0, stream>>>(expr, W1, b1, W2, b2, out);
    }
}

// Round 11
// 135.572 us; speedup vs baseline: 1.1457x; 1.0178x over previous
//
#include <hip/hip_runtime.h>
#include <math.h>

#define HID 64
#define KB 9            // NUM_BINS - 1
#define NB 10
#define NTOT (128 * 20000)
#define BLOCK 256
#define EPB 2048        // elements per block (main kernel)
#define FEPT 2          // fallback kernel elements/thread
#define LEAKY 0.01f
#define RSTRIDE 20      // floats per region row (9 A + 9 C + 2 pad) = 5 f4s
#define SENT 3.0e38f
#define LOG2E 1.44269504088896f

// bucket LUT for region search
#define NBUK 2048
#define BLO (-6.0f)
#define BSCALE (2048.0f / 12.0f)

#define TAB_U32 (128 + 65 * RSTRIDE)      // 1428 u32: 128 thresholds + 65 rows
#define WS_U32 (TAB_U32 + NBUK / 4)       // + 512 u32 of u8 buckets = 1940 (= 485 f4)
#define WS_BYTES (WS_U32 * 4)

typedef float v4f __attribute__((ext_vector_type(4)));
typedef float v2f __attribute__((ext_vector_type(2)));

// ---------------- setup: 97 blocks x 64 threads (unchanged from R9/R10) ----------------
__global__ __launch_bounds__(64) void setup_kernel(
    const float* __restrict__ W1, const float* __restrict__ b1,
    const float* __restrict__ W2, const float* __restrict__ b2,
    float* __restrict__ ws)
{
    __shared__ float t_lds[HID], w_lds[HID], b_lds[HID], tsrt[HID];
    __shared__ float w2_lds[HID * KB];
    __shared__ float red[18 * 65];   // rows padded to 65 -> conflict-free reduce

    const int j = threadIdx.x;       // unit index (original order)
    const int blk = blockIdx.x;
    const float w = W1[j], b = b1[j];
    const float t = (w != 0.0f) ? (-b / w) : -SENT;  // w==0: constant sign, park at -inf
    t_lds[j] = t; w_lds[j] = w; b_lds[j] = b;
    if (blk < 65) {
        #pragma unroll
        for (int q = j; q < HID * KB; q += 64) w2_lds[q] = W2[q];
    }
    __syncthreads();

    int rank = 0;                    // rank sort (unique ranks via index tiebreak)
    for (int i = 0; i < HID; ++i) {
        float ti = t_lds[i];
        rank += (ti < t || (ti == t && i < j)) ? 1 : 0;
    }
    tsrt[rank] = t;
    __syncthreads();

    if (blk >= 65) {                 // bucket fill
        const int bb = (blk - 65) * 64 + j;
        const float edge = BLO + ((float)bb - 0.5f) * (1.0f / BSCALE);  // half-bucket margin
        int cnt = 0;
        for (int i = 0; i < HID; ++i) cnt += (tsrt[i] <= edge) ? 1 : 0;
        ((unsigned char*)(ws + TAB_U32))[bb] = (bb == 0) ? 0 : (unsigned char)cnt;
        return;
    }

    const int r = blk;               // region index 0..64
    float xm;                        // point strictly inside region r
    if (r == 0)        xm = tsrt[0] - 1.0f;
    else if (r == HID) xm = tsrt[HID - 1] + 1.0f;
    else               xm = 0.5f * (tsrt[r - 1] + tsrt[r]);

    const float s = (fmaf(w, xm, b) >= 0.0f) ? 1.0f : LEAKY;
    #pragma unroll
    for (int k = 0; k < KB; ++k) {
        const float w2s = w2_lds[j * KB + k] * s;
        red[(2 * k) * 65 + j]     = w2s * w;   // A contribution
        red[(2 * k + 1) * 65 + j] = w2s * b;   // C contribution
    }
    __syncthreads();

    if (j < 18) {   // threads 0..17 each sum one row of 64 (deterministic order)
        float acc = 0.0f;
        for (int i = 0; i < HID; ++i) acc += red[j * 65 + i];
        const int k = j >> 1;
        if (j & 1) ws[128 + r * RSTRIDE + KB + k] = (acc + b2[k]) * LOG2E;  // C'
        else       ws[128 + r * RSTRIDE + k]      = acc * LOG2E;            // A'
    }
    if (r == 0) { ws[j] = tsrt[j]; ws[64 + j] = SENT; }
}

// ---------------- main: sparse two-phase (compaction) ----------------
// Phase 1: block loads 2048 expr values, compacts nonzero indices via
// ballot-free shfl scan, writes mask + CONSTANT default probs (zero-element
// pattern) as a dependency-free coalesced store stream.
// Phase 2 (after one barrier for WAW order): ~205 nonzeros/block get the
// table softmax and scatter-overwrite their 10 floats (5 float2, L2-hot).
__global__ __launch_bounds__(BLOCK) void main_kernel(
    const float* __restrict__ expr, const float* __restrict__ ws,
    float* __restrict__ out)
{
    __shared__ __align__(16) unsigned int sdata[WS_U32];   // ts | tab | buckets
    __shared__ float xs[EPB];
    __shared__ unsigned short list[EPB];
    __shared__ int swsum[4];

    const int tid = threadIdx.x;
    const int lane = tid & 63, wv = tid >> 6;

    // stage tables once per block
    #pragma unroll
    for (int t = tid; t < WS_U32 / 4; t += BLOCK)
        ((v4f*)sdata)[t] = ((const v4f*)ws)[t];

    // block's 2048 expr floats: 2 coalesced f4 loads/thread; stash to LDS
    const size_t e0 = (size_t)blockIdx.x * EPB;
    const v4f xa = ((const v4f*)(expr + e0))[tid];
    const v4f xb = ((const v4f*)(expr + e0))[BLOCK + tid];
    ((v4f*)xs)[tid] = xa;
    ((v4f*)xs)[BLOCK + tid] = xb;
    const float xr[8] = {xa.x, xa.y, xa.z, xa.w, xb.x, xb.y, xb.z, xb.w};

    int c = 0;
    #pragma unroll
    for (int j = 0; j < 8; ++j) c += (xr[j] != 0.0f) ? 1 : 0;

    // wave-inclusive scan of per-thread counts
    int incl = c;
    #pragma unroll
    for (int d = 1; d < 64; d <<= 1) {
        int n = __shfl_up(incl, d, 64);
        if (lane >= d) incl += n;
    }
    if (lane == 63) swsum[wv] = incl;
    __syncthreads();                 // xs + swsum visible

    const int s0 = swsum[0], s1 = swsum[1], s2 = swsum[2], s3 = swsum[3];
    const int total = s0 + s1 + s2 + s3;
    int base = (incl - c) + (wv > 0 ? s0 : 0) + (wv > 1 ? s1 : 0) + (wv > 2 ? s2 : 0);

    #pragma unroll
    for (int j = 0; j < 8; ++j) {
        if (xr[j] != 0.0f) {
            const int eidx = (j < 4) ? (4 * tid + j) : (1024 + 4 * tid + (j - 4));
            list[base++] = (unsigned short)eidx;
        }
    }

    // mask output: element-coalesced f4 stores
    float* mout = out + (size_t)NTOT * NB + e0;
    const v4f ma = {xr[0] != 0.f ? 1.f : 0.f, xr[1] != 0.f ? 1.f : 0.f,
                    xr[2] != 0.f ? 1.f : 0.f, xr[3] != 0.f ? 1.f : 0.f};
    const v4f mb = {xr[4] != 0.f ? 1.f : 0.f, xr[5] != 0.f ? 1.f : 0.f,
                    xr[6] != 0.f ? 1.f : 0.f, xr[7] != 0.f ? 1.f : 0.f};
    ((v4f*)mout)[tid] = ma;
    ((v4f*)mout)[BLOCK + tid] = mb;

    // default probs: constant zero-element pattern, lane-major linear f4s.
    // f4 g covers floats 4g..4g+3; component is 1 iff (4g+j)%10==0:
    // g%5==0 -> {1,0,0,0}; g%5==2 -> {0,0,1,0}; else zeros.
    float* gout = out + e0 * NB;
    #pragma unroll
    for (int q = 0; q < 20; ++q) {
        const int g = q * BLOCK + tid;
        const int r5 = g % 5;        // (q*256+t)%5 == (q+t)%5; compiler folds
        const v4f v = {r5 == 0 ? 1.0f : 0.0f, 0.0f, r5 == 2 ? 1.0f : 0.0f, 0.0f};
        ((v4f*)gout)[g] = v;
    }

    __syncthreads();   // list complete; defaults drained before scatters (WAW order)

    const float* ts  = (const float*)sdata;
    const float* tab = (const float*)sdata + 128;
    const unsigned char* buk = (const unsigned char*)(sdata + TAB_U32);

    for (int i = tid; i < total; i += BLOCK) {
        const int e = list[i];
        const float xe = xs[e];
        // bucket start (guaranteed <= region(xe)), then exact forward scan
        const float fb = fminf(2047.0f, fmaxf(0.0f, (xe - BLO) * BSCALE));
        int idx = buk[(int)fb];
        while (ts[idx] <= xe) ++idx;   // ts padded with SENT -> terminates, idx<=64
        const v4f* rowv = (const v4f*)(tab + idx * RSTRIDE);
        const v4f r0 = rowv[0], r1 = rowv[1], r2 = rowv[2], r3 = rowv[3], r4 = rowv[4];
        const float A[KB] = {r0.x, r0.y, r0.z, r0.w, r1.x, r1.y, r1.z, r1.w, r2.x};
        const float C[KB] = {r2.y, r2.z, r2.w, r3.x, r3.y, r3.z, r3.w, r4.x, r4.y};
        float lg[KB];   // base-2 logits (table pre-scaled by log2e)
        #pragma unroll
        for (int k = 0; k < KB; ++k) lg[k] = fmaf(A[k], xe, C[k]);
        float m = lg[0];
        #pragma unroll
        for (int k = 1; k < KB; ++k) m = fmaxf(m, lg[k]);
        float p[KB];
        float s = 0.0f;
        #pragma unroll
        for (int k = 0; k < KB; ++k) { p[k] = exp2f(lg[k] - m); s += p[k]; }
        const float rcp = __frcp_rn(s);
        // scatter: elem e's 10 floats = 5 float2 (8B-aligned: 40e bytes)
        v2f* po = (v2f*)(gout + (size_t)e * NB);
        po[0] = (v2f){0.0f,        p[0] * rcp};
        po[1] = (v2f){p[1] * rcp,  p[2] * rcp};
        po[2] = (v2f){p[3] * rcp,  p[4] * rcp};
        po[3] = (v2f){p[5] * rcp,  p[6] * rcp};
        po[4] = (v2f){p[7] * rcp,  p[8] * rcp};
    }
}

// ---------------- fallback if d_ws too small: self-contained, per-block table ----------------
__global__ __launch_bounds__(BLOCK) void fused_kernel(
    const float* __restrict__ expr,
    const float* __restrict__ W1, const float* __restrict__ b1,
    const float* __restrict__ W2, const float* __restrict__ b2,
    float* __restrict__ out)
{
    __shared__ float ts[128];
    __shared__ float tab[65 * RSTRIDE];
    __shared__ float st[HID], sw[HID], sb[HID], tsrt[HID];
    const int tid = threadIdx.x;
    if (tid < HID) {
        float w = W1[tid], b = b1[tid];
        st[tid] = (w != 0.0f) ? (-b / w) : -SENT;
        sw[tid] = w; sb[tid] = b;
    }
    __syncthreads();
    if (tid < HID) {
        float t = st[tid];
        int r = 0;
        for (int i = 0; i < HID; ++i) {
            float ti = st[i];
            r += (ti < t || (ti == t && i < tid)) ? 1 : 0;
        }
        tsrt[r] = t;
    }
    __syncthreads();
    if (tid < 128) ts[tid] = (tid < HID) ? tsrt[tid] : SENT;
    for (int item = tid; item < 65 * KB; item += BLOCK) {
        int r = item / KB, k = item - r * KB;
        float xm;
        if (r == 0)        xm = tsrt[0] - 1.0f;
        else if (r == HID) xm = tsrt[HID - 1] + 1.0f;
        else               xm = 0.5f * (tsrt[r - 1] + tsrt[r]);
        float A = 0.0f, C = b2[k];
        for (int j = 0; j < HID; ++j) {
            float w = sw[j], bb = sb[j];
            float s = (fmaf(w, xm, bb) >= 0.0f) ? 1.0f : LEAKY;
            float w2s = W2[j * KB + k] * s;
            A = fmaf(w2s, w, A);
            C = fmaf(w2s, bb, C);
        }
        tab[r * RSTRIDE + k] = A;
        tab[r * RSTRIDE + KB + k] = C;
    }
    __syncthreads();
    const int i0 = (blockIdx.x * BLOCK + tid) * FEPT;
    const float2 xv = *(const float2*)(expr + i0);
    float x[FEPT] = {xv.x, xv.y};
    float o[FEPT * NB]; float msk[FEPT];
    #pragma unroll
    for (int e = 0; e < FEPT; ++e) {
        const float xe = x[e];
        int idx = 0;
        #pragma unroll
        for (int s = 64; s >= 1; s >>= 1) idx += (ts[idx + s - 1] <= xe) ? s : 0;
        const float* row = tab + idx * RSTRIDE;
        float lg[KB];
        #pragma unroll
        for (int k = 0; k < KB; ++k) lg[k] = fmaf(row[k], xe, row[KB + k]);
        float m = lg[0];
        #pragma unroll
        for (int k = 1; k < KB; ++k) m = fmaxf(m, lg[k]);
        float p[KB]; float s = 0.0f;
        #pragma unroll
        for (int k = 0; k < KB; ++k) { p[k] = __expf(lg[k] - m); s += p[k]; }
        const float rcp = __frcp_rn(s);
        const bool nz = (xe != 0.0f);
        msk[e] = nz ? 1.0f : 0.0f;
        o[e * NB] = nz ? 0.0f : 1.0f;
        #pragma unroll
        for (int k = 0; k < KB; ++k) o[e * NB + 1 + k] = nz ? p[k] * rcp : 0.0f;
    }
    float* dst = out + (size_t)i0 * NB;
    #pragma unroll
    for (int q = 0; q < FEPT * NB / 4; ++q) ((float4*)dst)[q] = ((const float4*)o)[q];
    *(float2*)(out + (size_t)NTOT * NB + i0) = make_float2(msk[0], msk[1]);
}

extern "C" void kernel_launch(void* const* d_in, const int* in_sizes, int n_in,
                              void* d_out, int out_size, void* d_ws, size_t ws_size,
                              hipStream_t stream) {
    const float* expr = (const float*)d_in[0];
    const float* W1   = (const float*)d_in[1];
    const float* b1   = (const float*)d_in[2];
    const float* W2   = (const float*)d_in[3];
    const float* b2   = (const float*)d_in[4];
    float* out = (float*)d_out;

    if (ws_size >= (size_t)WS_BYTES) {
        float* ws = (float*)d_ws;
        setup_kernel<<<65 + NBUK / 64, 64, 0, stream>>>(W1, b1, W2, b2, ws);
        main_kernel<<<NTOT / EPB, BLOCK, 0, stream>>>(expr, ws, out);   // 1250 blocks
    } else {
        fused_kernel<<<NTOT / (BLOCK * FEPT), BLOCK, 0, stream>>>(expr, W1, b1, W2, b2, out);
    }
}